// Round 13
// baseline (271.826 us; speedup 1.0000x reference)
//
#include <hip/hip_runtime.h>
#include <hip/hip_bf16.h>
#include <math.h>

// Problem constants
#define D_MODEL 1024
#define D_STATE 16
#define D_INNER 2048
#define DT_RANK 64
#define BATCH 2
#define SEQ_LEN 1024
#define T_TOTAL (BATCH * SEQ_LEN)   // 2048 rows

// Scan chunking: h[16] per thread, one thread per (b, chunk, d)
#define NC 64
#define CL 16

// W_x GEMM split-K
#define KS 16
#define KC 128
#define KT 64

typedef unsigned short u16;
typedef __bf16 bf16x8 __attribute__((ext_vector_type(8)));
typedef float f32x4 __attribute__((ext_vector_type(4)));

__device__ __forceinline__ u16 f2bf(float f) {
    unsigned u = __builtin_bit_cast(unsigned, f);
    u += 0x7FFFu + ((u >> 16) & 1u);   // RNE
    return (u16)(u >> 16);
}

#define GLOAD_LDS16(g, l) \
    __builtin_amdgcn_global_load_lds((const __attribute__((address_space(1))) void*)(g), \
                                     (__attribute__((address_space(3))) void*)(l), 16, 0, 0)

// ---------------------------------------------------------------------------
// fp32 -> bf16 cast covering three arrays in one launch (1024 elems/block).
// ---------------------------------------------------------------------------
__global__ __launch_bounds__(256) void cast3_bf16_kernel(
    const float* __restrict__ in0, u16* __restrict__ out0, int nb0,
    const float* __restrict__ in1, u16* __restrict__ out1, int nb1,
    const float* __restrict__ in2, u16* __restrict__ out2)
{
    const float* in; u16* out; int i;
    if (blockIdx.x < nb0) {
        in = in0; out = out0; i = blockIdx.x * 256 + threadIdx.x;
    } else if (blockIdx.x < nb0 + nb1) {
        in = in1; out = out1; i = (blockIdx.x - nb0) * 256 + threadIdx.x;
    } else {
        in = in2; out = out2; i = (blockIdx.x - nb0 - nb1) * 256 + threadIdx.x;
    }
    float4 v = ((const float4*)in)[i];
    unsigned lo = (unsigned)f2bf(v.x) | ((unsigned)f2bf(v.y) << 16);
    unsigned hi = (unsigned)f2bf(v.z) | ((unsigned)f2bf(v.w) << 16);
    ((uint2*)out)[i] = make_uint2(lo, hi);
}

// ---------------------------------------------------------------------------
// bf16 MFMA GEMM, 8 waves (512 thr), 128x128 tile, BK=64 (2 gloads/operand,
// half the barrier-drain events of BK=32). Wave grid 2x4; wave tile 64x32.
// Optional K-split via gridDim.z: kbase = z*kchunk, C += z*csize.
// ---------------------------------------------------------------------------
__global__ __launch_bounds__(512) void gemm_bf16_8w(
    const u16* __restrict__ A, int lda,
    const u16* __restrict__ Bw, int ldb,
    float* __restrict__ C, int ldc, int kchunk, size_t csize)
{
    __shared__ u16 As[128][64];
    __shared__ u16 Bs[128][64];

    const int tid  = threadIdx.x;
    const int lane = tid & 63;
    const int wave = tid >> 6;          // 0..7
    const int wr   = wave >> 2;         // 0..1  (64-row half)
    const int wc   = wave & 3;          // 0..3  (32-col quarter)
    const int row0 = blockIdx.y * 128;
    const int col0 = blockIdx.x * 128;
    const int kbase = blockIdx.z * kchunk;

    C += (size_t)blockIdx.z * csize;

    // staging: 2 x 16B per thread per operand; each call covers 64 rows x 64 cols
    const int srow = tid >> 3;          // 0..63
    const int scol = (tid & 7) * 8;

    const u16* ag = A  + (size_t)(row0 + srow) * lda + scol;
    const u16* bg = Bw + (size_t)(col0 + srow) * ldb + scol;
    u16* asl = &As[0][0] + wave * 512;  // lane l -> u16 512w+8l = row 8w+(l>>3), col 8(l&7)
    u16* bsl = &Bs[0][0] + wave * 512;

    f32x4 acc[4][2];
#pragma unroll
    for (int m = 0; m < 4; ++m)
#pragma unroll
        for (int n = 0; n < 2; ++n)
            acc[m][n] = (f32x4){0.f, 0.f, 0.f, 0.f};

    const int fr = lane & 15;
    const int kh = (lane >> 4) * 8;

    for (int k0 = kbase; k0 < kbase + kchunk; k0 += 64) {
        GLOAD_LDS16(ag + k0,                     asl);
        GLOAD_LDS16(ag + k0 + (size_t)64 * lda,  asl + 4096);
        GLOAD_LDS16(bg + k0,                     bsl);
        GLOAD_LDS16(bg + k0 + (size_t)64 * ldb,  bsl + 4096);
        __syncthreads();

#pragma unroll
        for (int kk = 0; kk < 64; kk += 32) {
            bf16x8 af[4], bf[2];
#pragma unroll
            for (int m = 0; m < 4; ++m)
                af[m] = *(const bf16x8*)&As[wr * 64 + m * 16 + fr][kk + kh];
#pragma unroll
            for (int n = 0; n < 2; ++n)
                bf[n] = *(const bf16x8*)&Bs[wc * 32 + n * 16 + fr][kk + kh];
#pragma unroll
            for (int m = 0; m < 4; ++m)
#pragma unroll
                for (int n = 0; n < 2; ++n)
                    acc[m][n] = __builtin_amdgcn_mfma_f32_16x16x32_bf16(
                        af[m], bf[n], acc[m][n], 0, 0, 0);
        }
        __syncthreads();
    }

    const int crow = (lane >> 4) * 4;
#pragma unroll
    for (int m = 0; m < 4; ++m) {
        const int gr = row0 + wr * 64 + m * 16 + crow;
#pragma unroll
        for (int n = 0; n < 2; ++n) {
            const int gc = col0 + wc * 32 + n * 16 + fr;
#pragma unroll
            for (int r = 0; r < 4; ++r)
                C[(size_t)(gr + r) * ldc + gc] = acc[m][n][r];
        }
    }
}

// out = p0 + p1, float4 per thread
__global__ __launch_bounds__(256) void reduce2_kernel(
    const float* __restrict__ part, float* __restrict__ out, size_t n4)
{
    size_t i = (size_t)blockIdx.x * 256 + threadIdx.x;
    float4 a = ((const float4*)part)[i];
    float4 b = ((const float4*)part)[i + n4];
    ((float4*)out)[i] = make_float4(a.x + b.x, a.y + b.y, a.z + b.z, a.w + b.w);
}

// ---------------------------------------------------------------------------
// Split-K fp32 GEMM for dbc = xc @ W_x^T (M=2048, N=96, K=2048).
// ---------------------------------------------------------------------------
__global__ __launch_bounds__(256) void wx_partial(
    const float* __restrict__ A,
    const float* __restrict__ Bw,
    float* __restrict__ part)
{
    __shared__ float As[32][68];
    __shared__ float Bs[KT][98];

    const int tid = threadIdx.x;
    const int ks  = blockIdx.x;
    const int m0  = blockIdx.y * 32;
    const int k0  = ks * KC;

    const int tx = tid & 15;
    const int ty = tid >> 4;

    float acc[2][6] = {};

    for (int kk = 0; kk < KC; kk += KT) {
#pragma unroll
        for (int i = 0; i < 2; ++i) {
            int slot = tid + i * 256;
            int m  = slot >> 4;
            int kq = slot & 15;
            float4 v = *(const float4*)&A[(size_t)(m0 + m) * D_INNER + k0 + kk + kq * 4];
            *(float4*)&As[m][kq * 4] = v;
        }
#pragma unroll
        for (int i = 0; i < 6; ++i) {
            int slot = tid + i * 256;
            int n  = slot >> 4;
            int kq = slot & 15;
            float4 v = *(const float4*)&Bw[(size_t)n * D_INNER + k0 + kk + kq * 4];
            Bs[kq * 4 + 0][n] = v.x;
            Bs[kq * 4 + 1][n] = v.y;
            Bs[kq * 4 + 2][n] = v.z;
            Bs[kq * 4 + 3][n] = v.w;
        }
        __syncthreads();

#pragma unroll 8
        for (int k = 0; k < KT; ++k) {
            float a0 = As[ty * 2 + 0][k];
            float a1 = As[ty * 2 + 1][k];
            float2 b0 = *(const float2*)&Bs[k][tx * 6 + 0];
            float2 b1 = *(const float2*)&Bs[k][tx * 6 + 2];
            float2 b2 = *(const float2*)&Bs[k][tx * 6 + 4];
            float bv[6] = {b0.x, b0.y, b1.x, b1.y, b2.x, b2.y};
#pragma unroll
            for (int j = 0; j < 6; ++j) {
                acc[0][j] += a0 * bv[j];
                acc[1][j] += a1 * bv[j];
            }
        }
        __syncthreads();
    }

#pragma unroll
    for (int i = 0; i < 2; ++i) {
        size_t base = ((size_t)ks * T_TOTAL + (m0 + ty * 2 + i)) * 96 + tx * 6;
#pragma unroll
        for (int j = 0; j < 6; ++j)
            part[base + j] = acc[i][j];
    }
}

__global__ __launch_bounds__(256) void wx_reduce(
    const float* __restrict__ part, float* __restrict__ dbc)
{
    int i = blockIdx.x * 256 + threadIdx.x;
    float s = 0.f;
#pragma unroll
    for (int ks = 0; ks < KS; ++ks)
        s += part[(size_t)ks * T_TOTAL * 96 + i];
    dbc[i] = s;
}

// ---------------------------------------------------------------------------
// dt GEMM + fused bias+softplus.
// ---------------------------------------------------------------------------
__global__ __launch_bounds__(256) void dt_gemm(
    const float* __restrict__ A,
    const float* __restrict__ Bw,
    const float* __restrict__ bdt,
    float* __restrict__ dtb)
{
    __shared__ float As[16][65];
    __shared__ float Bs[16][65];

    const int tid = threadIdx.x;
    const int row0 = blockIdx.y * 64;
    const int col0 = blockIdx.x * 64;
    const int ty = tid >> 4;
    const int tx = tid & 15;

    float acc[4][4] = {};

    for (int k0 = 0; k0 < DT_RANK; k0 += 16) {
#pragma unroll
        for (int i = 0; i < 4; ++i) {
            int idx = tid + i * 256;
            int m = idx >> 4;
            int k = idx & 15;
            As[k][m] = A[(size_t)(row0 + m) * 96 + (k0 + k)];
        }
#pragma unroll
        for (int i = 0; i < 4; ++i) {
            int idx = tid + i * 256;
            int n = idx >> 4;
            int k = idx & 15;
            Bs[k][n] = Bw[(size_t)(col0 + n) * DT_RANK + (k0 + k)];
        }
        __syncthreads();

#pragma unroll
        for (int k = 0; k < 16; ++k) {
            float a[4], b[4];
#pragma unroll
            for (int i = 0; i < 4; ++i) a[i] = As[k][ty * 4 + i];
#pragma unroll
            for (int j = 0; j < 4; ++j) b[j] = Bs[k][tx * 4 + j];
#pragma unroll
            for (int i = 0; i < 4; ++i)
#pragma unroll
                for (int j = 0; j < 4; ++j)
                    acc[i][j] += a[i] * b[j];
        }
        __syncthreads();
    }

#pragma unroll
    for (int i = 0; i < 4; ++i) {
        int gm = row0 + ty * 4 + i;
#pragma unroll
        for (int j = 0; j < 4; ++j) {
            int gn = col0 + tx * 4 + j;
            float xv = acc[i][j] + bdt[gn];
            float sp = (xv > 20.f) ? xv : log1pf(__expf(xv));
            dtb[(size_t)gm * D_INNER + gn] = sp;
        }
    }
}

// ---------------------------------------------------------------------------
// Causal depthwise conv (K=4) + bias + SiLU.
// ---------------------------------------------------------------------------
__global__ __launch_bounds__(256) void conv_silu_kernel(
    const float* __restrict__ xz,
    const float* __restrict__ cw,
    const float* __restrict__ cb,
    float* __restrict__ xc)
{
    int idx = blockIdx.x * 256 + threadIdx.x;
    int d = idx & (D_INNER - 1);
    int t = (idx >> 11) & (SEQ_LEN - 1);
    int b = idx >> 21;

    const float* base = xz + ((size_t)b * SEQ_LEN + t) * (2 * D_INNER) + d;
    float w0 = cw[d * 4 + 0], w1 = cw[d * 4 + 1], w2 = cw[d * 4 + 2], w3 = cw[d * 4 + 3];
    float acc = cb[d];
    if (t >= 3) acc += w0 * base[-3 * (2 * D_INNER)];
    if (t >= 2) acc += w1 * base[-2 * (2 * D_INNER)];
    if (t >= 1) acc += w2 * base[-1 * (2 * D_INNER)];
    acc += w3 * base[0];
    float s = acc / (1.f + __expf(-acc));
    xc[idx] = s;
}

// ---------------------------------------------------------------------------
// Chunked selective scan, h[16]-in-registers (R10-validated).
// ---------------------------------------------------------------------------
__global__ __launch_bounds__(256) void scanA(
    const float* __restrict__ dbc,
    const float* __restrict__ dtv,
    const float* __restrict__ xc,
    const float* __restrict__ A_log,
    float* __restrict__ hbuf,
    float* __restrict__ sdt)
{
    __shared__ float sB[CL][16];

    const int tid = threadIdx.x;
    const int c = blockIdx.x;
    const int b = blockIdx.z;
    const int d = blockIdx.y * 256 + tid;
    const int t0 = c * CL;

    {
        int t = tid >> 4, e = tid & 15;
        sB[t][e] = dbc[(size_t)(b * SEQ_LEN + t0 + t) * 96 + DT_RANK + e];
    }

    float A[16];
#pragma unroll
    for (int i = 0; i < 4; ++i) {
        float4 v = *(const float4*)&A_log[d * 16 + i * 4];
        A[i * 4 + 0] = -__expf(v.x);
        A[i * 4 + 1] = -__expf(v.y);
        A[i * 4 + 2] = -__expf(v.z);
        A[i * 4 + 3] = -__expf(v.w);
    }
    __syncthreads();

    float h[16];
#pragma unroll
    for (int n = 0; n < 16; ++n) h[n] = 0.f;
    float sum = 0.f;

#pragma unroll 4
    for (int t = 0; t < CL; ++t) {
        size_t row = (size_t)(b * SEQ_LEN + t0 + t);
        float dtval = dtv[row * D_INNER + d];
        float xv    = xc [row * D_INNER + d];
        float w = xv * dtval;
        sum += dtval;
#pragma unroll
        for (int n = 0; n < 16; ++n) {
            float a = __expf(dtval * A[n]);
            h[n] = a * h[n] + w * sB[t][n];
        }
    }

    size_t o = (size_t)(b * NC + c) * 16 * D_INNER + d;
#pragma unroll
    for (int n = 0; n < 16; ++n)
        hbuf[o + (size_t)n * D_INNER] = h[n];
    sdt[(size_t)(b * NC + c) * D_INNER + d] = sum;
}

__global__ __launch_bounds__(256) void scanB(
    const float* __restrict__ A_log,
    const float* __restrict__ sdt,
    float* __restrict__ hbuf)
{
    int idx = blockIdx.x * 256 + threadIdx.x;
    int b  = idx >> 15;
    int nd = idx & 32767;
    int n  = nd >> 11;
    int d  = nd & (D_INNER - 1);

    const float A = -__expf(A_log[d * 16 + n]);
    float h = 0.f;
#pragma unroll 8
    for (int c = 0; c < NC; ++c) {
        size_t o = ((size_t)(b * NC + c) * 16 + n) * D_INNER + d;
        float tmp = hbuf[o];
        float P = __expf(A * sdt[(size_t)(b * NC + c) * D_INNER + d]);
        hbuf[o] = h;
        h = P * h + tmp;
    }
}

__global__ __launch_bounds__(256) void scanC(
    const float* __restrict__ dbc,
    const float* __restrict__ dtv,
    const float* __restrict__ xc,
    const float* __restrict__ xz,
    const float* __restrict__ A_log,
    const float* __restrict__ D_skip,
    const float* __restrict__ hbuf,
    u16* __restrict__ y)
{
    __shared__ float sB[CL][16];
    __shared__ float sC[CL][16];

    const int tid = threadIdx.x;
    const int c = blockIdx.x;
    const int b = blockIdx.z;
    const int d = blockIdx.y * 256 + tid;
    const int t0 = c * CL;

    {
        int t = tid >> 4, e = tid & 15;
        size_t row = (size_t)(b * SEQ_LEN + t0 + t);
        sB[t][e] = dbc[row * 96 + DT_RANK + e];
        sC[t][e] = dbc[row * 96 + DT_RANK + D_STATE + e];
    }

    float A[16];
#pragma unroll
    for (int i = 0; i < 4; ++i) {
        float4 v = *(const float4*)&A_log[d * 16 + i * 4];
        A[i * 4 + 0] = -__expf(v.x);
        A[i * 4 + 1] = -__expf(v.y);
        A[i * 4 + 2] = -__expf(v.z);
        A[i * 4 + 3] = -__expf(v.w);
    }
    const float Dv = D_skip[d];

    float h[16];
    size_t ho = (size_t)(b * NC + c) * 16 * D_INNER + d;
#pragma unroll
    for (int n = 0; n < 16; ++n)
        h[n] = hbuf[ho + (size_t)n * D_INNER];
    __syncthreads();

#pragma unroll 4
    for (int t = 0; t < CL; ++t) {
        size_t row = (size_t)(b * SEQ_LEN + t0 + t);
        float dtval = dtv[row * D_INNER + d];
        float xv    = xc [row * D_INNER + d];
        float zv    = xz [row * (2 * D_INNER) + D_INNER + d];
        float w = xv * dtval;
        float yv = 0.f;
#pragma unroll
        for (int n = 0; n < 16; ++n) {
            float a = __expf(dtval * A[n]);
            h[n] = a * h[n] + w * sB[t][n];
            yv += sC[t][n] * h[n];
        }
        float sig = 1.f / (1.f + __expf(-zv));
        y[row * D_INNER + d] = f2bf((yv + xv * Dv) * (zv * sig));
    }
}

// ---------------------------------------------------------------------------
// Launch
// ---------------------------------------------------------------------------
extern "C" void kernel_launch(void* const* d_in, const int* in_sizes, int n_in,
                              void* d_out, int out_size, void* d_ws, size_t ws_size,
                              hipStream_t stream)
{
    const float* x      = (const float*)d_in[0];
    const float* W_in   = (const float*)d_in[1];
    const float* conv_w = (const float*)d_in[2];
    const float* conv_b = (const float*)d_in[3];
    const float* W_x    = (const float*)d_in[4];
    const float* W_dt   = (const float*)d_in[5];
    const float* b_dt   = (const float*)d_in[6];
    const float* A_log  = (const float*)d_in[7];
    const float* D_skip = (const float*)d_in[8];
    const float* W_out  = (const float*)d_in[9];
    float* out = (float*)d_out;

    float* ws = (float*)d_ws;
    float* xz    = ws;                                  // 8,388,608 f
    float* xc    = xz + (size_t)8388608;                // 4,194,304 f
    float* dbc   = xc + (size_t)4194304;                //   196,608 f
    float* dtbuf = dbc + (size_t)196608;                // 4,194,304 f
    float* hbuf  = dtbuf + (size_t)4194304;             // 4,194,304 f
    float* sdt   = hbuf + (size_t)4194304;              //   262,144 f
    u16* ybf = (u16*)(sdt + (size_t)262144);            // 4,194,304 u16
    u16* xbf = ybf + (size_t)4194304;                   // 2,097,152 u16
    u16* wbf = xbf + (size_t)2097152;                   // 4,194,304 u16 (W_in)
    u16* wobf = wbf + (size_t)4194304;                  // 2,097,152 u16 (W_out)
    // wx split-K partials alias dtbuf (consumed before dt_gemm writes dtbuf).
    float* part = dtbuf;
    // GEMM7 split-K partials alias hbuf (scan complete by then); 2*2M floats.
    float* part7 = hbuf;

    // all three casts in one launch: x (2048 blk), W_in (4096), W_out (2048)
    cast3_bf16_kernel<<<8192, 256, 0, stream>>>(x, xbf, 2048,
                                                W_in, wbf, 4096,
                                                W_out, wobf);

    // 1. xz = x @ W_in^T (bf16 MFMA, 8-wave, BK=64): M=2048, N=4096, K=1024
    {
        dim3 grid(4096 / 128, 2048 / 128, 1);   // 512 blocks
        gemm_bf16_8w<<<grid, 512, 0, stream>>>(xbf, D_MODEL, wbf, D_MODEL,
                                               xz, 2 * D_INNER, D_MODEL, 0);
    }
    // 2. conv + silu
    conv_silu_kernel<<<(T_TOTAL * D_INNER) / 256, 256, 0, stream>>>(xz, conv_w, conv_b, xc);

    // 3. dbc = xc @ W_x^T : split-K fp32
    {
        dim3 grid(KS, T_TOTAL / 32);
        wx_partial<<<grid, 256, 0, stream>>>(xc, W_x, part);
        wx_reduce<<<(T_TOTAL * 96) / 256, 256, 0, stream>>>(part, dbc);
    }
    // 4+5. dt = softplus(dbc[:, :64] @ W_dt^T + b_dt)  (fused)
    {
        dim3 grid(D_INNER / 64, T_TOTAL / 64);
        dt_gemm<<<grid, 256, 0, stream>>>(dbc, W_dt, b_dt, dtbuf);
    }
    // 6. chunked selective scan (h-in-registers)
    {
        dim3 gridA(NC, D_INNER / 256, BATCH);
        scanA<<<gridA, 256, 0, stream>>>(dbc, dtbuf, xc, A_log, hbuf, sdt);
        scanB<<<(BATCH * D_STATE * D_INNER) / 256, 256, 0, stream>>>(A_log, sdt, hbuf);
        scanC<<<gridA, 256, 0, stream>>>(dbc, dtbuf, xc, xz,
                                         A_log, D_skip, hbuf, ybf);
    }
    // 7. out = y @ W_out^T (bf16 MFMA, 8-wave, BK=64, split-K=2): M=2048, N=1024, K=2048
    {
        dim3 grid(1024 / 128, 2048 / 128, 2);   // 256 blocks
        gemm_bf16_8w<<<grid, 512, 0, stream>>>(ybf, D_INNER, wobf, D_INNER,
                                               part7, D_MODEL, 1024,
                                               (size_t)T_TOTAL * D_MODEL);
        reduce2_kernel<<<(T_TOTAL * D_MODEL / 4) / 256, 256, 0, stream>>>(
            part7, out, (size_t)T_TOTAL * D_MODEL / 4);
    }
}